// Round 7
// baseline (1056.837 us; speedup 1.0000x reference)
//
#include <hip/hip_runtime.h>

#define T_OBS 512
#define BPB   8            // batches per block; 512 blocks -> 2 blocks/CU (independent barriers)
#define RSTRH 264          // halves per batch-row (132 dw, mod 32 = 4 -> only free b/b+? 2-way alias)
#define R32   132
#define PSTR  28
#define L2E   1.44269504089f

typedef float    f32x4 __attribute__((ext_vector_type(4)));
typedef _Float16 f16x8 __attribute__((ext_vector_type(8)));

#define MF(A,B,C) __builtin_amdgcn_mfma_f32_16x16x32_f16(A,B,C,0,0,0)

__device__ __forceinline__ unsigned f2h(float f){
    union { _Float16 h; unsigned short u; } v; v.h = (_Float16)f; return (unsigned)v.u;
}

// prescaled gates: i,f,o carry -log2e; g carries +2*log2e. 5 exp2 + 3 rcp.
__device__ __forceinline__ float act1(const f32x4 a, float& c){
    const float Ei=__builtin_amdgcn_exp2f(a[0]), Ef=__builtin_amdgcn_exp2f(a[1]);
    const float Eg=__builtin_amdgcn_exp2f(a[2]), Eo=__builtin_amdgcn_exp2f(a[3]);
    const float ui=1.f+Ei, uf=1.f+Ef, ug=1.f+Eg, uo=1.f+Eo;
    const float r1=__builtin_amdgcn_rcpf(ui*uf);
    const float ig=r1*uf, fg=r1*ui;
    const float r2=__builtin_amdgcn_rcpf(ug*uo);
    const float og=r2*ug, gg=fmaf(r2*uo,-2.f,1.f);
    c = fg*c + ig*gg;
    const float Ec=__builtin_amdgcn_exp2f(2.f*L2E*c);
    return og * fmaf(__builtin_amdgcn_rcpf(1.f+Ec),-2.f,1.f);
}

// tile-pair select: lanes q<8 keep own (tile 2j) quad; lanes q>=8 take tile 2j+1's quad
// from lane-8 via ds_swizzle xor-8 (BitMode offset 0x201F).
__device__ __forceinline__ f32x4 pick8(const f32x4 own, const f32x4 oth, const int half){
    f32x4 r;
    #pragma unroll
    for (int c2 = 0; c2 < 4; ++c2) {
        const float sw = __int_as_float(
            __builtin_amdgcn_ds_swizzle(__float_as_int(oth[c2]), 0x201F));
        r[c2] = half ? sw : own[c2];
    }
    return r;
}

// stored-col s -> unit: p=s>>1; u = 16*(p>>3) + 8*(s&1) + 4*((p>>2)&1) + (p&3)
// (store-order perm so each lane's two h are LDS-adjacent -> packed b32 writes)
__device__ __forceinline__ int s2u(const int s){
    const int p = s >> 1;
    return 16 * (p >> 3) + 8 * (s & 1) + 4 * ((p >> 2) & 1) + (p & 3);
}

// LDS per batch-row (halves, stride RSTRH): [0,64) h0 par0 | [64,128) h0 par1
//   | [128,192) h1 par0 (48 used) | [192,256) h1 par1 | pad. All h stored in sigma-order.
__global__ __launch_bounds__(384, 3) void lstm2_v7(
    const float* __restrict__ x,
    const float* __restrict__ Wih0, const float* __restrict__ Whh0,
    const float* __restrict__ bih0, const float* __restrict__ bhh0,
    const float* __restrict__ Wih1, const float* __restrict__ Whh1,
    const float* __restrict__ bih1, const float* __restrict__ bhh1,
    const float* __restrict__ Wlin, const float* __restrict__ blin,
    const int* __restrict__ fut,
    float* __restrict__ out)
{
    __shared__ __attribute__((aligned(16))) _Float16 s_h[BPB * RSTRH];
    __shared__ __attribute__((aligned(16))) float s_pr[2][BPB * PSTR];
    unsigned* const s32 = (unsigned*)s_h;

    const int tid  = threadIdx.x;
    const int wave = tid >> 6, lane = tid & 63;
    const int q    = lane & 15, rg = lane >> 4;
    const int b    = q & 7, half = q >> 3;
    const bool isL1 = (wave >= 3);          // waves 0-2: layer 0; 3-5: layer 1
    const int  w    = isL1 ? wave - 3 : wave;

    for (int i = tid; i < BPB * RSTRH; i += 384) s_h[i] = (_Float16)0.f;

    // gate of this lane's A-rows: row 16t+q -> gate = q&3
    const float sgl = ((q & 3) == 2) ? 2.f * L2E : -L2E;

    // ---- A fragments (4 M-tiles/wave), prescaled, fp16 hi/lo, sigma-permuted cols ----
    f16x8 ah[4][3], al[4][3];
    #pragma unroll
    for (int i = 0; i < 4; ++i) {
        const int t  = 4 * w + i;
        const int rp = 16 * t + q;
        const int r0 = (rp & 3) * 48 + (rp >> 2);
        #pragma unroll
        for (int s = 0; s < 3; ++s)
            #pragma unroll
            for (int j = 0; j < 8; ++j) {
                const int k0 = 32 * s + 8 * rg + j;
                float v = 0.f;
                if (isL1) {
                    const int kk = (k0 < 48) ? k0 : k0 - 48;
                    const int u  = s2u(kk);
                    v = ((k0 < 48) ? Wih1[r0 * 48 + u] : Whh1[r0 * 48 + u]) * sgl;
                } else if (s < 2 && k0 < 48) {
                    v = Whh0[r0 * 48 + s2u(k0)] * sgl;
                }
                const _Float16 hi = (_Float16)v;
                ah[i][s][j] = hi;
                al[i][s][j] = (_Float16)(v - (float)hi);
            }
    }

    const float sg4[4] = { -L2E, -L2E, 2.f * L2E, -L2E };   // (i,f,g,o)
    f32x4 bvt[4], wi0e[2];
    float wlq[2];
    #pragma unroll
    for (int i = 0; i < 4; ++i) {                  // per-tile bias (C-in), unit 16w+4i+rg
        const int u = 16 * w + 4 * i + rg;
        #pragma unroll
        for (int g = 0; g < 4; ++g)
            bvt[i][g] = (isL1 ? (bih1[g*48+u] + bhh1[g*48+u])
                              : (bih0[g*48+u] + bhh0[g*48+u])) * sg4[g];
    }
    #pragma unroll
    for (int j = 0; j < 2; ++j) {                  // per effective unit 16w+8j+4half+rg
        const int u = 16 * w + 8 * j + 4 * half + rg;
        wlq[j] = Wlin[u];
        #pragma unroll
        for (int g = 0; g < 4; ++g)
            wi0e[j][g] = Wih0[g * 48 + u] * sg4[g];
    }

    const int hb  = b * RSTRH;
    const int ko0 = 8 * rg;
    const int ko1 = (isL1 && rg >= 2) ? 112 + 8 * rg : 32 + 8 * rg;
    const int ko2 = 144 + 8 * rg;
    const int hwd = b * R32 + (isL1 ? 64 : 0) + 8 * w + 4 * half + rg;  // + cb/2 at use
    const int pw  = b * PSTR + 8 * w + 4 * half + rg;

    const int F    = fut[0];
    const int TT   = T_OBS + F;
    const int bb0  = blockIdx.x * BPB;
    const float bl = blin[0];
    const int xrow = (bb0 + b) * T_OBS;
    float cc0 = 0.f, cc1 = 0.f;
    const f32x4 z4 = { 0.f, 0.f, 0.f, 0.f };

    __syncthreads();

    // ---- tick 0 (peeled): h0(0) = act(bias + wi0*x0), h0(-1)=0 ----
    if (!isL1) {
        const float x0 = x[xrow];
        f32x4 a0 = bvt[half]     + wi0e[0] * x0;   // tile 2*0+half -> unit u_e(0)
        f32x4 a1 = bvt[2 + half] + wi0e[1] * x0;   // tile 2*1+half -> unit u_e(1)
        const float h0 = act1(a0, cc0);
        const float h1 = act1(a1, cc1);
        s32[hwd] = f2h(h0) | (f2h(h1) << 16);      // h0 par0 (cb=0)
    }
    __syncthreads();
    float xcur = isL1 ? 0.f : x[xrow + 1];

    // steady tick: L0 computes step TAU_, L1 computes step TAU_-1; one barrier.
#define STEADY(TAU_, CB_, PB_, WP_) do {                                          \
    if (!isL1) {                                                                  \
        const float xnxt = x[xrow + (((TAU_) + 1 < T_OBS) ? (TAU_) + 1 : T_OBS - 1)]; \
        if ((TAU_) >= 2 && tid < 8) {                                             \
            const float* pr = &s_pr[(WP_) ^ 1][tid * PSTR];                       \
            const f32x4 sv = *(const f32x4*)(pr)      + *(const f32x4*)(pr + 4)   \
                           + *(const f32x4*)(pr + 8)  + *(const f32x4*)(pr + 12)  \
                           + *(const f32x4*)(pr + 16) + *(const f32x4*)(pr + 20); \
            out[(bb0 + tid) * TT + ((TAU_) - 2)] = sv[0]+sv[1]+sv[2]+sv[3]+bl;    \
        }                                                                         \
        const f16x8 B0 = *(const f16x8*)(s_h + hb + (PB_) + ko0);                 \
        const f16x8 B1 = *(const f16x8*)(s_h + hb + (PB_) + ko1);                 \
        f32x4 acc[4];                                                             \
        _Pragma("unroll")                                                         \
        for (int i = 0; i < 4; ++i) {                                             \
            f32x4 A = MF(ah[i][0], B0, bvt[i]);                                   \
            A = MF(al[i][0], B0, A);                                              \
            f32x4 Bq = MF(ah[i][1], B1, z4);                                      \
            Bq = MF(al[i][1], B1, Bq);                                            \
            acc[i] = A + Bq;                                                      \
        }                                                                         \
        f32x4 g0 = pick8(acc[0], acc[1], half) + wi0e[0] * xcur;                  \
        f32x4 g1 = pick8(acc[2], acc[3], half) + wi0e[1] * xcur;                  \
        const float h0 = act1(g0, cc0);                                           \
        const float h1 = act1(g1, cc1);                                           \
        s32[hwd + ((CB_) >> 1)] = f2h(h0) | (f2h(h1) << 16);                      \
        xcur = xnxt;                                                              \
    } else {                                                                      \
        const f16x8 B0 = *(const f16x8*)(s_h + hb + (PB_) + ko0);                 \
        const f16x8 B1 = *(const f16x8*)(s_h + hb + (PB_) + ko1);                 \
        const f16x8 B2 = *(const f16x8*)(s_h + hb + (PB_) + ko2);                 \
        f32x4 acc[4];                                                             \
        _Pragma("unroll")                                                         \
        for (int i = 0; i < 4; ++i) {                                             \
            f32x4 A = MF(ah[i][0], B0, bvt[i]);                                   \
            A = MF(al[i][0], B0, A);                                              \
            A = MF(ah[i][1], B1, A);                                              \
            f32x4 Bq = MF(al[i][1], B1, z4);                                      \
            Bq = MF(ah[i][2], B2, Bq);                                            \
            Bq = MF(al[i][2], B2, Bq);                                            \
            acc[i] = A + Bq;                                                      \
        }                                                                         \
        const f32x4 g0 = pick8(acc[0], acc[1], half);                             \
        const f32x4 g1 = pick8(acc[2], acc[3], half);                             \
        const float h0 = act1(g0, cc0);                                           \
        const float h1 = act1(g1, cc1);                                           \
        s32[hwd + ((CB_) >> 1)] = f2h(h0) | (f2h(h1) << 16);                      \
        s_pr[WP_][pw] = fmaf(h1, wlq[1], h0 * wlq[0]);                            \
    }                                                                             \
    __syncthreads();                                                              \
} while (0)

    for (int tau = 1; tau < T_OBS - 1; tau += 2) {
        STEADY(tau,     64, 0, 1);    // tau odd
        STEADY(tau + 1,  0, 64, 0);   // tau+1 even
    }
    STEADY(T_OBS - 1, 64, 0, 1);      // tau = 511

    // bridge: out(510) from s_pr parity 1 (written at tau=511)
    if (tid < 8) {
        const float* pr = &s_pr[1][tid * PSTR];
        const f32x4 sv = *(const f32x4*)(pr)      + *(const f32x4*)(pr + 4)
                       + *(const f32x4*)(pr + 8)  + *(const f32x4*)(pr + 12)
                       + *(const f32x4*)(pr + 16) + *(const f32x4*)(pr + 20);
        out[(bb0 + tid) * TT + (T_OBS - 2)] = sv[0] + sv[1] + sv[2] + sv[3] + bl;
    }

    // ---- AR loop: o(tau-1) resolved mid-tick ----
    for (int tau = T_OBS; tau <= TT; ++tau) {
        const int cb = (tau & 1) * 64;
        const int pb = cb ^ 64;
        f32x4 g0, g1;
        if (isL1) {
            const f16x8 B0 = *(const f16x8*)(s_h + hb + pb + ko0);
            const f16x8 B1 = *(const f16x8*)(s_h + hb + pb + ko1);
            const f16x8 B2 = *(const f16x8*)(s_h + hb + pb + ko2);
            f32x4 acc[4];
            #pragma unroll
            for (int i = 0; i < 4; ++i) {
                f32x4 A = MF(ah[i][0], B0, bvt[i]);
                A = MF(al[i][0], B0, A);
                A = MF(ah[i][1], B1, A);
                f32x4 Bq = MF(al[i][1], B1, z4);
                Bq = MF(ah[i][2], B2, Bq);
                Bq = MF(al[i][2], B2, Bq);
                acc[i] = A + Bq;
            }
            g0 = pick8(acc[0], acc[1], half);
            g1 = pick8(acc[2], acc[3], half);
            const float h0 = act1(g0, cc0);
            const float h1 = act1(g1, cc1);
            s32[hwd + (cb >> 1)] = f2h(h0) | (f2h(h1) << 16);
            s_pr[tau & 1][pw] = fmaf(h1, wlq[1], h0 * wlq[0]);
        } else {
            const f16x8 B0 = *(const f16x8*)(s_h + hb + pb + ko0);
            const f16x8 B1 = *(const f16x8*)(s_h + hb + pb + ko1);
            f32x4 acc[4];
            #pragma unroll
            for (int i = 0; i < 4; ++i) {
                f32x4 A = MF(ah[i][0], B0, bvt[i]);
                A = MF(al[i][0], B0, A);
                f32x4 Bq = MF(ah[i][1], B1, z4);
                Bq = MF(al[i][1], B1, Bq);
                acc[i] = A + Bq;
            }
            g0 = pick8(acc[0], acc[1], half);
            g1 = pick8(acc[2], acc[3], half);
        }
        __syncthreads();   // mid: s_pr (h1(tau-1) partials) ready

        if (!isL1) {
            const float* pr = &s_pr[tau & 1][b * PSTR];
            const f32x4 sv = *(const f32x4*)(pr)      + *(const f32x4*)(pr + 4)
                           + *(const f32x4*)(pr + 8)  + *(const f32x4*)(pr + 12)
                           + *(const f32x4*)(pr + 16) + *(const f32x4*)(pr + 20);
            const float o = sv[0] + sv[1] + sv[2] + sv[3] + bl;
            if (tid < 8) out[(bb0 + tid) * TT + (tau - 1)] = o;
            if (tau < TT) {
                g0 += wi0e[0] * o;
                g1 += wi0e[1] * o;
                const float h0 = act1(g0, cc0);
                const float h1 = act1(g1, cc1);
                s32[hwd + (cb >> 1)] = f2h(h0) | (f2h(h1) << 16);
            }
        }
        __syncthreads();
    }
}

extern "C" void kernel_launch(void* const* d_in, const int* in_sizes, int n_in,
                              void* d_out, int out_size, void* d_ws, size_t ws_size,
                              hipStream_t stream) {
    const float* x    = (const float*)d_in[0];
    const float* Wih0 = (const float*)d_in[1];
    const float* Whh0 = (const float*)d_in[2];
    const float* bih0 = (const float*)d_in[3];
    const float* bhh0 = (const float*)d_in[4];
    const float* Wih1 = (const float*)d_in[5];
    const float* Whh1 = (const float*)d_in[6];
    const float* bih1 = (const float*)d_in[7];
    const float* bhh1 = (const float*)d_in[8];
    const float* Wlin = (const float*)d_in[9];
    const float* blin = (const float*)d_in[10];
    const int*   fut  = (const int*)d_in[11];
    float* out = (float*)d_out;

    const int B    = in_sizes[0] / T_OBS;   // 4096
    const int grid = B / BPB;               // 512 blocks -> 2 independent blocks per CU
    lstm2_v7<<<grid, 384, 0, stream>>>(
        x, Wih0, Whh0, bih0, bhh0, Wih1, Whh1, bih1, bhh1, Wlin, blin, fut, out);
}

// Round 8
// 512.885 us; speedup vs baseline: 2.0606x; 2.0606x over previous
//
#include <hip/hip_runtime.h>

#define T_OBS 512
#define RSTRH 264          // halves per batch-row (132 dw; 4q mod 32 spread -> conflict-free)
#define PSTR  28           // s_pr row stride (dwords)
#define L2E   1.44269504089f

typedef float    f32x4 __attribute__((ext_vector_type(4)));
typedef _Float16 f16x8 __attribute__((ext_vector_type(8)));

#define MF(A,B,C) __builtin_amdgcn_mfma_f32_16x16x32_f16(A,B,C,0,0,0)

__device__ __forceinline__ unsigned f2h(float f){
    union { _Float16 h; unsigned short u; } v; v.h=(_Float16)f; return (unsigned)v.u;
}

// prescaled gates: i,f,o carry -log2e; g carries +2*log2e.
// single-rcp gates: R = rcp(ui*uf*ug*uo); recover all four via products. 5 exp2 + 2 rcp.
__device__ __forceinline__ float act1(const f32x4 a, float& c){
    const float Ei=__builtin_amdgcn_exp2f(a[0]), Ef=__builtin_amdgcn_exp2f(a[1]);
    const float Eg=__builtin_amdgcn_exp2f(a[2]), Eo=__builtin_amdgcn_exp2f(a[3]);
    const float ui=1.f+Ei, uf=1.f+Ef, ug=1.f+Eg, uo=1.f+Eo;
    const float P=ui*uf, Q=ug*uo;
    const float R=__builtin_amdgcn_rcpf(P*Q);
    const float aP=R*Q, aQ=R*P;                 // 1/(ui*uf), 1/(ug*uo)
    const float ig=aP*uf, fg=aP*ui;             // sigmoids
    const float og=aQ*ug;
    const float gg=fmaf(aQ*uo,-2.f,1.f);        // tanh(g)
    c = fg*c + ig*gg;
    const float Ec=__builtin_amdgcn_exp2f(2.f*L2E*c);
    return og*fmaf(__builtin_amdgcn_rcpf(1.f+Ec),-2.f,1.f);
}

// sigma store layout: stored position p holds unit 8*(p>>3) + 4*(p&1) + ((p&7)>>1)
// (so lane (q,rg) of wave w writes its two units at adjacent halves 8w+2rg+{0,1})
__device__ __forceinline__ int u_of_pos(const int p){
    return 8*(p>>3) + 4*(p&1) + ((p&7)>>1);
}

// LDS per batch-row q (halves, stride RSTRH):
//   [0,48) h0 par0 | [48,64) pad0 | [64,112) h0 par1 | [112,128) pad0
//   [128,176) h1 par0 | [176,192) pad | [192,240) h1 par1 | [240,264) pad
__global__ __launch_bounds__(768, 1) void lstm2_v8(
    const float* __restrict__ x,
    const float* __restrict__ Wih0, const float* __restrict__ Whh0,
    const float* __restrict__ bih0, const float* __restrict__ bhh0,
    const float* __restrict__ Wih1, const float* __restrict__ Whh1,
    const float* __restrict__ bih1, const float* __restrict__ bhh1,
    const float* __restrict__ Wlin, const float* __restrict__ blin,
    const int* __restrict__ fut,
    float* __restrict__ out)
{
    __shared__ __attribute__((aligned(16))) _Float16 s_h[16 * RSTRH];
    __shared__ __attribute__((aligned(16))) float s_pr[2][16 * PSTR];
    unsigned* const s32 = (unsigned*)s_h;

    const int tid  = threadIdx.x;
    const int wave = tid >> 6, lane = tid & 63;
    const int q    = lane & 15, rg = lane >> 4;
    const bool isL1 = (wave >= 6);          // waves 0-5: layer 0; 6-11: layer 1
    const int  w    = isL1 ? wave - 6 : wave;

    for (int i = tid; i < 16 * RSTRH; i += 768) s_h[i] = (_Float16)0.f;

    // gate of this lane's A-rows: rp = 16t+q -> gate = q&3 (uniform per lane)
    const float sgl = ((q & 3) == 2) ? 2.f * L2E : -L2E;

    // ---- A fragments (2 tiles/wave), prescaled, fp16 hi/lo, sigma-permuted k-cols ----
    f16x8 ah[2][3], al[2][3];
    #pragma unroll
    for (int i = 0; i < 2; ++i) {
        const int t  = 2 * w + i;
        const int rp = 16 * t + q;
        const int r0 = (rp & 3) * 48 + (rp >> 2);
        #pragma unroll
        for (int s = 0; s < 3; ++s)
            #pragma unroll
            for (int j = 0; j < 8; ++j) {
                const int p = 32 * s + 8 * rg + j;
                float v = 0.f;
                if (isL1) v = ((p < 48) ? Wih1[r0 * 48 + u_of_pos(p)]
                                        : Whh1[r0 * 48 + u_of_pos(p - 48)]) * sgl;
                else if (p < 48) v = Whh0[r0 * 48 + u_of_pos(p)] * sgl;
                const _Float16 hi = (_Float16)v;
                ah[i][s][j] = hi;
                al[i][s][j] = (_Float16)(v - (float)hi);
            }
    }

    const float sg4[4] = { -L2E, -L2E, 2.f * L2E, -L2E };   // (i,f,g,o)
    f32x4 bvt[2], wi0v[2];
    float wlq[2];
    #pragma unroll
    for (int i = 0; i < 2; ++i) {
        const int u = 8 * w + 4 * i + rg;      // unit of this lane's act quad i
        wlq[i] = Wlin[u];
        #pragma unroll
        for (int g = 0; g < 4; ++g) {
            bvt[i][g]  = (isL1 ? (bih1[g*48+u] + bhh1[g*48+u])
                               : (bih0[g*48+u] + bhh0[g*48+u])) * sg4[g];
            wi0v[i][g] = Wih0[g * 48 + u] * sg4[g];
        }
    }

    // B-frag k-offsets (pre-parity): chunks never straddle the 48 boundary
    int koff[3];
    #pragma unroll
    for (int s = 0; s < 3; ++s) {
        const int p0 = 32 * s + 8 * rg;
        koff[s] = p0 + ((p0 >= 48) ? 80 : 0);   // h1 region sits +128 at p=48
    }

    const int F    = fut[0];
    const int TT   = T_OBS + F;
    const int bb0  = blockIdx.x * 16;
    const float bl = blin[0];
    const int xrow = (bb0 + q) * T_OBS;
    const int nbh  = q * RSTRH;
    const int hwp  = nbh + (isL1 ? 128 : 0) + 8 * w + 2 * rg;  // + CB at use (even)
    const int prw  = q * PSTR + 4 * w + rg;

    float cc0 = 0.f, cc1 = 0.f;
    const f32x4 z4 = { 0.f, 0.f, 0.f, 0.f };

    __syncthreads();

    // ---- tick 0 (peeled): h0(0) = act(bias + wi0*x0), h0(-1)=0 ----
    if (!isL1) {
        const float x0 = x[xrow];
        const f32x4 a0 = bvt[0] + wi0v[0] * x0;
        const f32x4 a1 = bvt[1] + wi0v[1] * x0;
        const unsigned h0 = f2h(act1(a0, cc0));
        const unsigned h1 = f2h(act1(a1, cc1));
        s32[hwp >> 1] = h0 | (h1 << 16);        // h0 par0 (CB=0)
    }
    __syncthreads();
    float xcur = isL1 ? 0.f : x[xrow + 1];

    // steady tick: L0 computes step TAU_, L1 computes step TAU_-1; one barrier.
#define STEADY(TAU_, CB_, PB_) do {                                              \
    if (!isL1) {                                                                 \
        const float xnxt = x[xrow + (((TAU_) + 1 < T_OBS) ? (TAU_) + 1 : T_OBS - 1)]; \
        if ((TAU_) >= 2 && wave == 0) {        /* lane-parallel head gather */   \
            const int nn = lane >> 2, j0 = lane & 3;                             \
            const float* pr = &s_pr[((TAU_) - 1) & 1][nn * PSTR];                \
            float sg = pr[j0] + pr[j0+4] + pr[j0+8] + pr[j0+12]                  \
                     + pr[j0+16] + pr[j0+20];                                    \
            sg += __shfl_xor(sg, 1); sg += __shfl_xor(sg, 2);                    \
            if (j0 == 0) out[(bb0 + nn) * TT + ((TAU_) - 2)] = sg + bl;          \
        }                                                                        \
        const f16x8 B0 = *(const f16x8*)(s_h + nbh + (PB_) + koff[0]);           \
        const f16x8 B1 = *(const f16x8*)(s_h + nbh + (PB_) + koff[1]);           \
        f32x4 Aq[2], Bq[2];                                                      \
        _Pragma("unroll")                                                        \
        for (int i = 0; i < 2; ++i) {                                            \
            Aq[i] = MF(ah[i][0], B0, bvt[i]);                                    \
            Aq[i] = MF(al[i][0], B0, Aq[i]);                                     \
            Bq[i] = MF(ah[i][1], B1, z4);                                        \
            Bq[i] = MF(al[i][1], B1, Bq[i]);                                     \
        }                                                                        \
        const f32x4 a0 = Aq[0] + Bq[0] + wi0v[0] * xcur;                         \
        const f32x4 a1 = Aq[1] + Bq[1] + wi0v[1] * xcur;                         \
        const unsigned h0 = f2h(act1(a0, cc0));                                  \
        const unsigned h1 = f2h(act1(a1, cc1));                                  \
        s32[(hwp + (CB_)) >> 1] = h0 | (h1 << 16);                               \
        xcur = xnxt;                                                             \
    } else {                                                                     \
        const f16x8 B0 = *(const f16x8*)(s_h + nbh + (PB_) + koff[0]);           \
        const f16x8 B1 = *(const f16x8*)(s_h + nbh + (PB_) + koff[1]);           \
        const f16x8 B2 = *(const f16x8*)(s_h + nbh + (PB_) + koff[2]);           \
        f32x4 Aq[2], Bq[2];                                                      \
        _Pragma("unroll")                                                        \
        for (int i = 0; i < 2; ++i) {                                            \
            Aq[i] = MF(ah[i][0], B0, bvt[i]);                                    \
            Aq[i] = MF(al[i][0], B0, Aq[i]);                                     \
            Aq[i] = MF(ah[i][1], B1, Aq[i]);                                     \
            Bq[i] = MF(al[i][1], B1, z4);                                        \
            Bq[i] = MF(ah[i][2], B2, Bq[i]);                                     \
            Bq[i] = MF(al[i][2], B2, Bq[i]);                                     \
        }                                                                        \
        const f32x4 a0 = Aq[0] + Bq[0];                                          \
        const f32x4 a1 = Aq[1] + Bq[1];                                          \
        const float h0 = act1(a0, cc0);                                          \
        const float h1 = act1(a1, cc1);                                          \
        s32[(hwp + (CB_)) >> 1] = f2h(h0) | (f2h(h1) << 16);                     \
        s_pr[(TAU_) & 1][prw] = fmaf(h1, wlq[1], h0 * wlq[0]);                   \
    }                                                                            \
    __syncthreads();                                                             \
} while (0)

    // ---- steady loop: tau = 1..511, 2x unrolled with compile-time parity ----
    for (int tau = 1; tau < T_OBS - 1; tau += 2) {
        STEADY(tau,     64, 0);    // tau odd
        STEADY(tau + 1,  0, 64);   // tau+1 even
    }
    STEADY(T_OBS - 1, 64, 0);      // tau = 511

    // bridge: out(510) from s_pr parity 1 (written at tau=511)
    if (tid < 16) {
        const float* pr = &s_pr[1][tid * PSTR];
        const f32x4 sv = *(const f32x4*)(pr)      + *(const f32x4*)(pr + 4)
                       + *(const f32x4*)(pr + 8)  + *(const f32x4*)(pr + 12)
                       + *(const f32x4*)(pr + 16) + *(const f32x4*)(pr + 20);
        out[(bb0 + tid) * TT + (T_OBS - 2)] = sv[0] + sv[1] + sv[2] + sv[3] + bl;
    }

    // ---- AR loop: tau = 512..TT; o(tau-1) resolved mid-tick ----
    for (int tau = T_OBS; tau <= TT; ++tau) {
        const int cb = (tau & 1) * 64;
        const int pb = cb ^ 64;

        f32x4 Aq[2], Bq[2];
        if (isL1) {
            const f16x8 B0 = *(const f16x8*)(s_h + nbh + pb + koff[0]);
            const f16x8 B1 = *(const f16x8*)(s_h + nbh + pb + koff[1]);
            const f16x8 B2 = *(const f16x8*)(s_h + nbh + pb + koff[2]);
            #pragma unroll
            for (int i = 0; i < 2; ++i) {
                Aq[i] = MF(ah[i][0], B0, bvt[i]);
                Aq[i] = MF(al[i][0], B0, Aq[i]);
                Aq[i] = MF(ah[i][1], B1, Aq[i]);
                Bq[i] = MF(al[i][1], B1, z4);
                Bq[i] = MF(ah[i][2], B2, Bq[i]);
                Bq[i] = MF(al[i][2], B2, Bq[i]);
            }
            const f32x4 a0 = Aq[0] + Bq[0];
            const f32x4 a1 = Aq[1] + Bq[1];
            const float h0 = act1(a0, cc0);
            const float h1 = act1(a1, cc1);
            s32[(hwp + cb) >> 1] = f2h(h0) | (f2h(h1) << 16);
            s_pr[tau & 1][prw] = fmaf(h1, wlq[1], h0 * wlq[0]);
        } else {
            const f16x8 B0 = *(const f16x8*)(s_h + nbh + pb + koff[0]);
            const f16x8 B1 = *(const f16x8*)(s_h + nbh + pb + koff[1]);
            #pragma unroll
            for (int i = 0; i < 2; ++i) {
                Aq[i] = MF(ah[i][0], B0, bvt[i]);
                Aq[i] = MF(al[i][0], B0, Aq[i]);
                Bq[i] = MF(ah[i][1], B1, z4);
                Bq[i] = MF(al[i][1], B1, Bq[i]);
            }
        }
        __syncthreads();   // mid: s_pr (h1(tau-1) partials) ready

        if (!isL1) {
            const float* pr = &s_pr[tau & 1][q * PSTR];
            const f32x4 sv = *(const f32x4*)(pr)      + *(const f32x4*)(pr + 4)
                           + *(const f32x4*)(pr + 8)  + *(const f32x4*)(pr + 12)
                           + *(const f32x4*)(pr + 16) + *(const f32x4*)(pr + 20);
            const float o = sv[0] + sv[1] + sv[2] + sv[3] + bl;
            if (tid < 16) out[(bb0 + q) * TT + (tau - 1)] = o;
            if (tau < TT) {
                const f32x4 a0 = Aq[0] + Bq[0] + wi0v[0] * o;
                const f32x4 a1 = Aq[1] + Bq[1] + wi0v[1] * o;
                const unsigned h0 = f2h(act1(a0, cc0));
                const unsigned h1 = f2h(act1(a1, cc1));
                s32[(hwp + cb) >> 1] = h0 | (h1 << 16);
            }
        }
        __syncthreads();
    }
}

extern "C" void kernel_launch(void* const* d_in, const int* in_sizes, int n_in,
                              void* d_out, int out_size, void* d_ws, size_t ws_size,
                              hipStream_t stream) {
    const float* x    = (const float*)d_in[0];
    const float* Wih0 = (const float*)d_in[1];
    const float* Whh0 = (const float*)d_in[2];
    const float* bih0 = (const float*)d_in[3];
    const float* bhh0 = (const float*)d_in[4];
    const float* Wih1 = (const float*)d_in[5];
    const float* Whh1 = (const float*)d_in[6];
    const float* bih1 = (const float*)d_in[7];
    const float* bhh1 = (const float*)d_in[8];
    const float* Wlin = (const float*)d_in[9];
    const float* blin = (const float*)d_in[10];
    const int*   fut  = (const int*)d_in[11];
    float* out = (float*)d_out;

    const int B    = in_sizes[0] / T_OBS;   // 4096
    const int grid = B / 16;                // 256 blocks -> 1 per CU, 12 waves = 3/SIMD
    lstm2_v8<<<grid, 768, 0, stream>>>(
        x, Wih0, Whh0, bih0, bhh0, Wih1, Whh1, bih1, bhh1, Wlin, blin, fut, out);
}